// Round 11
// baseline (270.126 us; speedup 1.0000x reference)
//
#include <hip/hip_runtime.h>

#define DEV __device__ __forceinline__

typedef unsigned short u16;
typedef float  floatx4 __attribute__((ext_vector_type(4)));
typedef unsigned int uintx2 __attribute__((ext_vector_type(2)));
typedef unsigned int uintx4 __attribute__((ext_vector_type(4)));
typedef __bf16 bf16x8 __attribute__((ext_vector_type(8)));

constexpr int cB = 4, cLQ = 1024, cLKV = 2048, cD = 1024, cH = 16, cHD = 64;

DEV u16 f2bf(float f) {
  unsigned u = __builtin_bit_cast(unsigned, f);
  u += 0x7fffu + ((u >> 16) & 1u);       // round-to-nearest-even
  return (u16)(u >> 16);
}

DEV bf16x8 ld_frag(const u16* p) {
  uintx4 u = *(const uintx4*)p;
  return __builtin_bit_cast(bf16x8, u);
}

DEV floatx4 mfma16(bf16x8 a, bf16x8 b, floatx4 c) {
  return __builtin_amdgcn_mfma_f32_16x16x32_bf16(a, b, c, 0, 0, 0);
}

DEV float ex2(float x) { return __builtin_amdgcn_exp2f(x); }

// pack two f32 -> u32 of 2 bf16 (truncating; P is positive, bias ~0.1%).
DEV unsigned pkbf(float a, float b) {
  return (__builtin_bit_cast(unsigned, b) & 0xffff0000u) |
         (__builtin_bit_cast(unsigned, a) >> 16);
}

// gfx950 dual-register row swaps (VALU, not LDS). HW-validated in v14b.
DEV void pl32(unsigned &a, unsigned &b) {
#if __has_builtin(__builtin_amdgcn_permlane32_swap)
  uintx2 r = __builtin_amdgcn_permlane32_swap(a, b, false, false);
  a = r[0]; b = r[1];
#else
  asm("v_permlane32_swap_b32 %0, %1" : "+v"(a), "+v"(b));
#endif
}
DEV void pl16(unsigned &a, unsigned &b) {
#if __has_builtin(__builtin_amdgcn_permlane16_swap)
  uintx2 r = __builtin_amdgcn_permlane16_swap(a, b, false, false);
  a = r[0]; b = r[1];
#else
  asm("v_permlane16_swap_b32 %0, %1" : "+v"(a), "+v"(b));
#endif
}

// ---------------------------------------------------------------------------
// prep v16 (validated r10): LN one wave per row, no barriers, no LDS.
//   [0, 3072):      LN rows (4 per block)
//   [3072, 4096):   W casts fp32->bf16 (4 float4 per thread)
//   4096:           lens from mask + len-descending batch order
// ---------------------------------------------------------------------------
__global__ __launch_bounds__(256) void prep_kernel(
    const float* __restrict__ q, const float* __restrict__ kv,
    const float* __restrict__ nqw, const float* __restrict__ nqb,
    const float* __restrict__ nkw, const float* __restrict__ nkb,
    u16* __restrict__ qn, u16* __restrict__ kvn,
    const float* __restrict__ Wq, const float* __restrict__ Wkv,
    const float* __restrict__ Wo, u16* __restrict__ wqb,
    u16* __restrict__ wkvb, u16* __restrict__ wob,
    const void* __restrict__ mask, int* __restrict__ lens) {
  int bid = blockIdx.x, tid = threadIdx.x;
  if (bid < 3072) {                       // LayerNorm, one WAVE per row
    int row = bid * 4 + (tid >> 6);
    int lane = tid & 63;
    const float* x; const float* w; const float* b; u16* dst;
    if (row < cB * cLQ) {
      x = q + (size_t)row * cD; w = nqw; b = nqb; dst = qn + (size_t)row * cD;
    } else {
      int r2 = row - cB * cLQ;
      x = kv + (size_t)r2 * cD; w = nkw; b = nkb; dst = kvn + (size_t)r2 * cD;
    }
    const float4* xf = (const float4*)x;
    float4 v[4];
    #pragma unroll
    for (int c = 0; c < 4; c++) v[c] = xf[lane + 64 * c];
    float s = 0.f;
    #pragma unroll
    for (int c = 0; c < 4; c++) s += (v[c].x + v[c].y) + (v[c].z + v[c].w);
    #pragma unroll
    for (int m = 1; m < 64; m <<= 1) s += __shfl_xor(s, m, 64);
    float mean = s * (1.f / cD);
    float ss = 0.f;
    #pragma unroll
    for (int c = 0; c < 4; c++) {
      v[c].x -= mean; v[c].y -= mean; v[c].z -= mean; v[c].w -= mean;
      ss += (v[c].x * v[c].x + v[c].y * v[c].y) +
            (v[c].z * v[c].z + v[c].w * v[c].w);
    }
    #pragma unroll
    for (int m = 1; m < 64; m <<= 1) ss += __shfl_xor(ss, m, 64);
    float rs = rsqrtf(ss * (1.f / cD) + 1e-5f);
    const float4* wf = (const float4*)w;
    const float4* bf = (const float4*)b;
    #pragma unroll
    for (int c = 0; c < 4; c++) {
      float4 wv = wf[lane + 64 * c];
      float4 bv = bf[lane + 64 * c];
      ushort4 o;
      o.x = f2bf(v[c].x * rs * wv.x + bv.x);
      o.y = f2bf(v[c].y * rs * wv.y + bv.y);
      o.z = f2bf(v[c].z * rs * wv.z + bv.z);
      o.w = f2bf(v[c].w * rs * wv.w + bv.w);
      ((ushort4*)dst)[lane + 64 * c] = o;
    }
  } else if (bid < 4096) {                // weight casts, 4 float4/thread
    int base = (bid - 3072) * 1024;
    #pragma unroll
    for (int c = 0; c < 4; c++) {
      int gi = base + c * 256 + tid;      // quad idx 0..1M
      const float* src; u16* dst; int off;
      if (gi < 262144)      { src = Wq;  dst = wqb;  off = gi; }
      else if (gi < 786432) { src = Wkv; dst = wkvb; off = gi - 262144; }
      else                  { src = Wo;  dst = wob;  off = gi - 786432; }
      float4 v = ((const float4*)src)[off];
      ushort4 o;
      o.x = f2bf(v.x); o.y = f2bf(v.y); o.z = f2bf(v.z); o.w = f2bf(v.w);
      ((ushort4*)dst)[off] = o;
    }
  } else {                                // lens (monotone suffix mask)
    __shared__ int smode;
    __shared__ int cnt[cB];
    if (tid == 0) smode = 0;
    if (tid < cB) cnt[tid] = 0;
    __syncthreads();
    const unsigned* mi = (const unsigned*)mask;
    int bad = 0;
    for (int i = tid; i < cB * cLKV / 4; i += 256)
      if (mi[i] > 1u) bad = 1;
    if (bad) smode = 1;
    __syncthreads();
    if (smode == 0) {                     // int32 mask
      for (int b = 0; b < cB; b++) {
        int c = 0;
        for (int i = tid; i < cLKV; i += 256) c += (mi[(size_t)b * cLKV + i] == 0u);
        atomicAdd(&cnt[b], c);
      }
    } else {                              // uint8 mask
      const unsigned char* m8 = (const unsigned char*)mask;
      for (int b = 0; b < cB; b++) {
        int c = 0;
        for (int i = tid; i < cLKV; i += 256) c += (m8[(size_t)b * cLKV + i] == 0);
        atomicAdd(&cnt[b], c);
      }
    }
    __syncthreads();
    if (tid < cB) lens[tid] = cnt[tid];
    if (tid == 0) {                       // order[4] = batches, len-descending
      int ord[4] = {0, 1, 2, 3};
      #pragma unroll
      for (int a = 0; a < 3; a++)
        #pragma unroll
        for (int d = 0; d < 3; d++)
          if (cnt[ord[d]] < cnt[ord[d + 1]]) {
            int tswap = ord[d]; ord[d] = ord[d + 1]; ord[d + 1] = tswap;
          }
      #pragma unroll
      for (int a = 0; a < 4; a++) lens[4 + a] = ord[a];
    }
  }
}

// ---------------------------------------------------------------------------
// proj v17: 256x128 tile, 4 waves each owning 128x64 (acc 8x4) — the attn-q32
// mechanism applied to GEMM: per wave per K-step, 12 ds_reads feed 32 MFMA
// (ratio 0.375 vs 0.5 at 128²), staging 6 writes/thread amortized over 2x
// work -> total DS-ops per unit work -25%. The 128² structure was LDS-pipe-
// bound (MfmaUtil 18-27% vs ~40% cap); this attacks exactly that term.
// Same proven v9 skeleton: VGPR-prefetch + ping-pong LDS, ONE barrier/K-iter.
// __launch_bounds__(256,2): acc 128 + frags 48 + prefetch 24 + addr ~= 215
// VGPR -> 2 waves/SIMD. LDS = 2*(256+128)*32*2 = 48 KB.
// Grid 640: [0,128) Q-proj (16x8 tiles of 256x128), [128,640) KV-proj
// (32x16). Mask-skip carries over: tile_start = 256k >= len implies
// 256*ceil(len/256) >= 64*ceil(len/64) -> outputs never read by attn.
// ---------------------------------------------------------------------------
__global__ __launch_bounds__(256, 2) void proj_fused(
    const u16* __restrict__ qn, const u16* __restrict__ wqb,
    const float* __restrict__ bq, u16* __restrict__ qhb,
    const u16* __restrict__ kvn, const u16* __restrict__ wkvb,
    const float* __restrict__ bkv, u16* __restrict__ khb,
    u16* __restrict__ vthb, const int* __restrict__ lens) {
  __shared__ __align__(16) u16 As[2 * 256 * 32];   // 32 KB
  __shared__ __align__(16) u16 Bs[2 * 128 * 32];   // 16 KB
  int bid = blockIdx.x;
  int tid = threadIdx.x;
  int lane = tid & 63;
  int m16 = lane & 15, quad = lane >> 4;
  int wave = tid >> 6;
  int wr = wave >> 1, wc = wave & 1;      // wave: rows wr*128+, cols wc*64+

  bool isQ = bid < 128;
  int row0, col0;
  const u16* A; const u16* Bm; const float* bias;
  if (isQ) {
    row0 = (bid >> 3) * 256; col0 = (bid & 7) * 128;
    A = qn; Bm = wqb; bias = bq;
  } else {
    int b2 = bid - 128;
    row0 = (b2 >> 4) * 256; col0 = (b2 & 15) * 128;
    A = kvn; Bm = wkvb; bias = bkv;
    if ((row0 & (cLKV - 1)) >= lens[row0 >> 11]) return;  // masked tile skip
  }
  const int K = cD;

  // staging map: thread covers A rows srow+{0,64,128,192}, B rows srow+{0,64}
  int srow = tid >> 2;                    // 0..63
  int sseg = (tid & 3) * 8;
  const u16* ga = A + (size_t)(row0 + srow) * K + sseg;
  const u16* gb = Bm + (size_t)(col0 + srow) * K + sseg;
  const size_t rstep = (size_t)64 * K;
  int woff = srow * 32 + sseg;

  // tile 0 -> buf0
  uintx4 a0 = *(const uintx4*)ga;
  uintx4 a1 = *(const uintx4*)(ga + rstep);
  uintx4 a2 = *(const uintx4*)(ga + 2 * rstep);
  uintx4 a3 = *(const uintx4*)(ga + 3 * rstep);
  uintx4 b0 = *(const uintx4*)gb;
  uintx4 b1 = *(const uintx4*)(gb + rstep);
  *(uintx4*)(As + woff) = a0;
  *(uintx4*)(As + woff + 2048) = a1;
  *(uintx4*)(As + woff + 4096) = a2;
  *(uintx4*)(As + woff + 6144) = a3;
  *(uintx4*)(Bs + woff) = b0;
  *(uintx4*)(Bs + woff + 2048) = b1;
  // prefetch tile 1
  a0 = *(const uintx4*)(ga + 32);
  a1 = *(const uintx4*)(ga + rstep + 32);
  a2 = *(const uintx4*)(ga + 2 * rstep + 32);
  a3 = *(const uintx4*)(ga + 3 * rstep + 32);
  b0 = *(const uintx4*)(gb + 32);
  b1 = *(const uintx4*)(gb + rstep + 32);
  __syncthreads();

  floatx4 z = {0.f, 0.f, 0.f, 0.f};
  floatx4 acc[8][4];
  #pragma unroll
  for (int i = 0; i < 8; i++)
    #pragma unroll
    for (int j = 0; j < 4; j++) acc[i][j] = z;

  for (int k0 = 0; k0 < K; k0 += 32) {
    int cur = (k0 >> 5) & 1;
    const u16* rA = As + cur * 8192;
    const u16* rB = Bs + cur * 4096;
    bf16x8 af[8], bfr[4];
    #pragma unroll
    for (int i = 0; i < 8; i++)
      af[i] = ld_frag(&rA[(wr * 128 + i * 16 + m16) * 32 + quad * 8]);
    #pragma unroll
    for (int j = 0; j < 4; j++)
      bfr[j] = ld_frag(&rB[(wc * 64 + j * 16 + m16) * 32 + quad * 8]);
    if (k0 + 32 < K) {                    // stage next tile into other buffer
      u16* nA = As + (cur ^ 1) * 8192 + woff;
      u16* nB = Bs + (cur ^ 1) * 4096 + woff;
      *(uintx4*)nA = a0;
      *(uintx4*)(nA + 2048) = a1;
      *(uintx4*)(nA + 4096) = a2;
      *(uintx4*)(nA + 6144) = a3;
      *(uintx4*)nB = b0;
      *(uintx4*)(nB + 2048) = b1;
      if (k0 + 64 < K) {                  // prefetch tile k0+64
        a0 = *(const uintx4*)(ga + k0 + 64);
        a1 = *(const uintx4*)(ga + rstep + k0 + 64);
        a2 = *(const uintx4*)(ga + 2 * rstep + k0 + 64);
        a3 = *(const uintx4*)(ga + 3 * rstep + k0 + 64);
        b0 = *(const uintx4*)(gb + k0 + 64);
        b1 = *(const uintx4*)(gb + rstep + k0 + 64);
      }
    }
    #pragma unroll
    for (int i = 0; i < 8; i++)
      #pragma unroll
      for (int j = 0; j < 4; j++)
        acc[i][j] = mfma16(af[i], bfr[j], acc[i][j]);
    __syncthreads();
  }

  // epilogue: C/D layout col=lane&15, row=quad*4+reg
  #pragma unroll
  for (int j = 0; j < 4; j++) {
    int col = col0 + wc * 64 + j * 16 + m16;
    float bs = bias[col];
    if (isQ) {
      #pragma unroll
      for (int i = 0; i < 8; i++) {
        int crow = row0 + wr * 128 + i * 16 + quad * 4;
        #pragma unroll
        for (int r = 0; r < 4; r++)
          qhb[(size_t)(crow + r) * cD + col] =
              f2bf((acc[i][j][r] + bs) * 0.18033688f);   // 0.125 * log2(e)
      }
    } else {
      bool isK = col < cD;
      int c2 = isK ? col : col - cD;
      int hh = c2 >> 6, dd = c2 & 63;
      #pragma unroll
      for (int i = 0; i < 8; i++) {
        int crow = row0 + wr * 128 + i * 16 + quad * 4;
        int bb = crow >> 11, kvp = crow & (cLKV - 1);
        if (isK) {
          u16* dst = khb + ((size_t)(bb * cH + hh) * cLKV + kvp) * 64 + dd;
          #pragma unroll
          for (int r = 0; r < 4; r++) dst[(size_t)r * 64] = f2bf(acc[i][j][r] + bs);
        } else {
          u16* dst = vthb + ((size_t)(bb * cH + hh) * 64 + dd) * cLKV + kvp;
          ushort4 o;
          o.x = f2bf(acc[i][j][0] + bs);
          o.y = f2bf(acc[i][j][1] + bs);
          o.z = f2bf(acc[i][j][2] + bs);
          o.w = f2bf(acc[i][j][3] + bs);
          *(ushort4*)dst = o;
        }
      }
    }
  }
}

// ---------------------------------------------------------------------------
// O-proj v16 (validated r10): 64x128 tiles -> 512 blocks @ 24KB LDS, all
// co-resident (2 blocks/CU). Per-wave 32x64 output (acc[2][4]).
// ---------------------------------------------------------------------------
__global__ __launch_bounds__(256) void gemm_o(
    const u16* __restrict__ A, const u16* __restrict__ Bm,
    const float* __restrict__ bias, const float* __restrict__ res,
    float* __restrict__ Cout, int N, int K) {
  __shared__ __align__(16) u16 As[2 * 64 * 32];    //  8 KB
  __shared__ __align__(16) u16 Bs[2 * 128 * 32];   // 16 KB
  int lane = threadIdx.x & 63;
  int m16 = lane & 15, quad = lane >> 4;
  int wave = threadIdx.x >> 6;
  int wr = wave >> 1, wc = wave & 1;
  int row0 = blockIdx.y * 64, col0 = blockIdx.x * 128;

  int tid = threadIdx.x;
  int srow = tid >> 2;                    // 0..63
  int sseg = (tid & 3) * 8;
  const u16* ga = A + (size_t)(row0 + srow) * K + sseg;
  const u16* gb = Bm + (size_t)(col0 + srow) * K + sseg;
  const size_t rstep = (size_t)64 * K;
  int woff = srow * 32 + sseg;

  // tile 0 -> buf0
  uintx4 a0 = *(const uintx4*)ga;
  uintx4 b0 = *(const uintx4*)gb;
  uintx4 b1 = *(const uintx4*)(gb + rstep);
  *(uintx4*)(As + woff) = a0;
  *(uintx4*)(Bs + woff) = b0;
  *(uintx4*)(Bs + woff + 2048) = b1;
  // prefetch tile 1
  a0 = *(const uintx4*)(ga + 32);
  b0 = *(const uintx4*)(gb + 32);
  b1 = *(const uintx4*)(gb + rstep + 32);
  __syncthreads();

  floatx4 z = {0.f, 0.f, 0.f, 0.f};
  floatx4 acc[2][4];
  #pragma unroll
  for (int i = 0; i < 2; i++)
    #pragma unroll
    for (int j = 0; j < 4; j++) acc[i][j] = z;

  for (int k0 = 0; k0 < K; k0 += 32) {
    int cur = (k0 >> 5) & 1;
    const u16* rA = As + cur * 2048;
    const u16* rB = Bs + cur * 4096;
    bf16x8 af[2], bfr[4];
    #pragma unroll
    for (int i = 0; i < 2; i++)
      af[i] = ld_frag(&rA[(wr * 32 + i * 16 + m16) * 32 + quad * 8]);
    #pragma unroll
    for (int j = 0; j < 4; j++)
      bfr[j] = ld_frag(&rB[(wc * 64 + j * 16 + m16) * 32 + quad * 8]);
    if (k0 + 32 < K) {                    // stage next tile into other buffer
      u16* nA = As + (cur ^ 1) * 2048 + woff;
      u16* nB = Bs + (cur ^ 1) * 4096 + woff;
      *(uintx4*)nA = a0;
      *(uintx4*)nB = b0;
      *(uintx4*)(nB + 2048) = b1;
      if (k0 + 64 < K) {                  // prefetch tile k0+64
        a0 = *(const uintx4*)(ga + k0 + 64);
        b0 = *(const uintx4*)(gb + k0 + 64);
        b1 = *(const uintx4*)(gb + rstep + k0 + 64);
      }
    }
    #pragma unroll
    for (int i = 0; i < 2; i++)
      #pragma unroll
      for (int j = 0; j < 4; j++)
        acc[i][j] = mfma16(af[i], bfr[j], acc[i][j]);
    __syncthreads();
  }

  #pragma unroll
  for (int j = 0; j < 4; j++) {
    int col = col0 + wc * 64 + j * 16 + m16;
    float bs = bias[col];
    #pragma unroll
    for (int i = 0; i < 2; i++) {
      int crow = row0 + wr * 32 + i * 16 + quad * 4;
      #pragma unroll
      for (int r = 0; r < 4; r++) {
        size_t idx = (size_t)(crow + r) * N + col;
        Cout[idx] = acc[i][j][r] + bs + res[idx];
      }
    }
  }
}

// ---------------------------------------------------------------------------
// Flash cross-attention v14 (HW-validated round 8): q32 structure + P path
// fully in registers via dual-register permlane swaps (8 swaps + 8 packs per
// group replace 12 DS ops/chunk). LDS 18.4 KB.
// ---------------------------------------------------------------------------
constexpr int KS = 72;   // K/V LDS row stride (u16): 144 B, 16B-aligned

template<bool MASK>
DEV void attn_compute(int k0, int len, const u16* __restrict__ Kt,
                      const u16* __restrict__ Vt,
                      const bf16x8 (&qf)[2][2], int m16, int quad,
                      float (&lsum)[2], floatx4 (&accO)[2][4]) {
  floatx4 z = {0.f, 0.f, 0.f, 0.f};
  // K fragments loaded ONCE, used by both q-groups.
  // QK^T swapped: A = K (row = kv = t*16+m16, k = d), B = Q (col = q)
  bf16x8 kf[4][2];
  #pragma unroll
  for (int t = 0; t < 4; t++) {
    kf[t][0] = ld_frag(&Kt[(t * 16 + m16) * KS + quad * 8]);
    kf[t][1] = ld_frag(&Kt[(t * 16 + m16) * KS + 32 + quad * 8]);
  }
  floatx4 s[2][4];
  #pragma unroll
  for (int g = 0; g < 2; g++)
    #pragma unroll
    for (int t = 0; t < 4; t++) {
      floatx4 tt = z;
      tt = mfma16(kf[t][0], qf[g][0], tt);
      tt = mfma16(kf[t][1], qf[g][1], tt);
      s[g][t] = tt;
    }
  // exp2 -> packed bf16 pairs in regs; p[t][j]: j-th bf16x2 of tile t
  bf16x8 ap0[2], ap1[2];
  #pragma unroll
  for (int g = 0; g < 2; g++) {
    unsigned p[4][2];
    #pragma unroll
    for (int t = 0; t < 4; t++) {
      float e0, e1, e2, e3;
      if (MASK) {
        int key = k0 + t * 16 + quad * 4;
        e0 = (key     < len) ? ex2(s[g][t][0]) : 0.f;
        e1 = (key + 1 < len) ? ex2(s[g][t][1]) : 0.f;
        e2 = (key + 2 < len) ? ex2(s[g][t][2]) : 0.f;
        e3 = (key + 3 < len) ? ex2(s[g][t][3]) : 0.f;
      } else {
        e0 = ex2(s[g][t][0]);
        e1 = ex2(s[g][t][1]);
        e2 = ex2(s[g][t][2]);
        e3 = ex2(s[g][t][3]);
      }
      lsum[g] += (e0 + e1) + (e2 + e3);
      p[t][0] = pkbf(e0, e1);
      p[t][1] = pkbf(e2, e3);
    }
    // redistribute: 2 swaps per register pair, no selects
    unsigned a0 = p[0][0], b0 = p[1][0]; pl32(a0, b0); pl16(a0, b0);
    unsigned a1 = p[0][1], b1 = p[1][1]; pl32(a1, b1); pl16(a1, b1);
    uintx4 lo = {a0, a1, b0, b1};
    unsigned c0 = p[2][0], d0 = p[3][0]; pl32(c0, d0); pl16(c0, d0);
    unsigned c1 = p[2][1], d1 = p[3][1]; pl32(c1, d1); pl16(c1, d1);
    uintx4 hi = {c0, c1, d0, d1};
    ap0[g] = __builtin_bit_cast(bf16x8, lo);   // kv 0..31 (k = quad*8+0..7)
    ap1[g] = __builtin_bit_cast(bf16x8, hi);   // kv 32..63
  }
  // PV: A = P in regs (row = q, k = kv), B = V (col = d); bv loaded once
  // for both groups.
  #pragma unroll
  for (int db = 0; db < 4; db++) {
    bf16x8 bv0 = ld_frag(&Vt[(db * 16 + m16) * KS + quad * 8]);
    bf16x8 bv1 = ld_frag(&Vt[(db * 16 + m16) * KS + 32 + quad * 8]);
    #pragma unroll
    for (int g = 0; g < 2; g++) {
      accO[g][db] = mfma16(ap0[g], bv0, accO[g][db]);
      accO[g][db] = mfma16(ap1[g], bv1, accO[g][db]);
    }
  }
}

__global__ __launch_bounds__(256) void attn_kernel(
    const u16* __restrict__ qh, const u16* __restrict__ kh,
    const u16* __restrict__ vth, const int* __restrict__ lens,
    u16* __restrict__ out) {
  int bid = blockIdx.x;                   // 0..511
  int r = bid >> 7;                       // 0..3
  int rank = r ^ (r >> 1);                // {0,1,3,2}: pair long+short per CU
  int b = lens[4 + rank];
  int combo = bid & 127;
  int h = combo >> 3;                     // 0..15
  int qt = combo & 7;                     // 0..7 (128 q-rows per block)
  int len = lens[b];
  int wave = threadIdx.x >> 6, lane = threadIdx.x & 63;
  int m16 = lane & 15, quad = lane >> 4;

  __shared__ __align__(16) u16 Kt[64 * KS];
  __shared__ __align__(16) u16 Vt[64 * KS];

  // Q as B-operand: two 16-q groups per wave; col = q, k = d
  int q0 = qt * 128 + wave * 32;
  const u16* qp = qh + ((size_t)(b * cLQ + q0 + m16) * cH + h) * cHD;
  bf16x8 qf[2][2];
  qf[0][0] = ld_frag(qp + quad * 8);
  qf[0][1] = ld_frag(qp + 32 + quad * 8);
  qf[1][0] = ld_frag(qp + (size_t)16 * cD + quad * 8);
  qf[1][1] = ld_frag(qp + (size_t)16 * cD + 32 + quad * 8);

  const u16* kbase = kh + (size_t)(b * cH + h) * cLKV * cHD;
  const u16* vbase = vth + (size_t)(b * cH + h) * cHD * cLKV;

  int srow = threadIdx.x >> 3;   // 0..31
  int sseg = threadIdx.x & 7;    // 0..7 (16B segment)
  const u16* kg = kbase + (size_t)srow * cHD + sseg * 8;
  const u16* vg = vbase + (size_t)srow * cLKV + sseg * 8;

  float lsum[2] = {0.f, 0.f};
  floatx4 z = {0.f, 0.f, 0.f, 0.f};
  floatx4 accO[2][4] = {{z, z, z, z}, {z, z, z, z}};

  int nch = (len + 63) >> 6;
  // prefetch chunk 0
  uintx4 ka  = *(const uintx4*)kg;
  uintx4 kb2 = *(const uintx4*)(kg + (size_t)32 * cHD);
  uintx4 va  = *(const uintx4*)vg;
  uintx4 vb  = *(const uintx4*)(vg + (size_t)32 * cLKV);

  for (int c = 0; c < nch; c++) {
    int k0 = c * 64;
    __syncthreads();
    *(uintx4*)&Kt[srow * KS + sseg * 8] = ka;
    *(uintx4*)&Kt[(srow + 32) * KS + sseg * 8] = kb2;
    *(uintx4*)&Vt[srow * KS + sseg * 8] = va;
    *(uintx4*)&Vt[(srow + 32) * KS + sseg * 8] = vb;
    if (c + 1 < nch) {
      int kn = k0 + 64;
      ka  = *(const uintx4*)(kg + (size_t)kn * cHD);
      kb2 = *(const uintx4*)(kg + (size_t)(kn + 32) * cHD);
      va  = *(const uintx4*)(vg + kn);
      vb  = *(const uintx4*)(vg + (size_t)32 * cLKV + kn);
    }
    __syncthreads();
    if (k0 + 64 <= len)
      attn_compute<false>(k0, len, Kt, Vt, qf, m16, quad, lsum, accO);
    else
      attn_compute<true>(k0, len, Kt, Vt, qf, m16, quad, lsum, accO);
  }

  // softmax denominators per group: lane owns q = g*16+m16; reduce quads
  #pragma unroll
  for (int g = 0; g < 2; g++) {
    float tsum = lsum[g];
    tsum += __shfl_xor(tsum, 16, 64);
    tsum += __shfl_xor(tsum, 32, 64);
    #pragma unroll
    for (int rr = 0; rr < 4; rr++) {
      float inv = 1.0f / __shfl(tsum, quad * 4 + rr, 16);
      int qg = q0 + g * 16 + quad * 4 + rr;
      size_t base = ((size_t)(b * cLQ + qg) * cH + h) * cHD;
      #pragma unroll
      for (int db = 0; db < 4; db++)
        out[base + db * 16 + m16] = f2bf(accO[g][db][rr] * inv);
    }
  }
}

// ---------------------------------------------------------------------------
extern "C" void kernel_launch(void* const* d_in, const int* in_sizes, int n_in,
                              void* d_out, int out_size, void* d_ws, size_t ws_size,
                              hipStream_t stream) {
  const float* q    = (const float*)d_in[0];
  const float* kv   = (const float*)d_in[1];
  const void*  mask = d_in[2];
  const float* nqw  = (const float*)d_in[3];
  const float* nqb  = (const float*)d_in[4];
  const float* nkw  = (const float*)d_in[5];
  const float* nkb  = (const float*)d_in[6];
  const float* Wq   = (const float*)d_in[7];
  const float* bq   = (const float*)d_in[8];
  const float* Wkv  = (const float*)d_in[9];
  const float* bkv  = (const float*)d_in[10];
  const float* Wo   = (const float*)d_in[11];
  const float* bo   = (const float*)d_in[12];
  float* out = (float*)d_out;

  char* w = (char*)d_ws;
  int* lens = (int*)w;       w += 256;
  u16* qn   = (u16*)w;       w += (size_t)cB * cLQ * cD * 2;        // 8 MB
  u16* kvn  = (u16*)w;       w += (size_t)cB * cLKV * cD * 2;       // 16 MB
  u16* wqb  = (u16*)w;       w += (size_t)cD * cD * 2;              // 2 MB
  u16* wkvb = (u16*)w;       w += (size_t)2 * cD * cD * 2;          // 4 MB
  u16* wob  = (u16*)w;       w += (size_t)cD * cD * 2;              // 2 MB
  u16* qhb  = (u16*)w;       w += (size_t)cB * cLQ * cD * 2;        // 8 MB
  u16* khb  = (u16*)w;       w += (size_t)cB * cH * cLKV * cHD * 2; // 16 MB
  u16* vthb = (u16*)w;       w += (size_t)cB * cH * cHD * cLKV * 2; // 16 MB
  u16* aob  = (u16*)w;                                              // 8 MB

  prep_kernel<<<4097, 256, 0, stream>>>(
      q, kv, nqw, nqb, nkw, nkb, qn, kvn,
      Wq, Wkv, Wo, wqb, wkvb, wob, mask, lens);
  proj_fused<<<640, 256, 0, stream>>>(
      qn, wqb, bq, qhb, kvn, wkvb, bkv, khb, vthb, lens);
  attn_kernel<<<512, 256, 0, stream>>>(
      qhb, khb, vthb, lens, aob);
  gemm_o<<<dim3(cD / 128, cB * cLQ / 64), 256, 0, stream>>>(
      aob, wob, bo, q, out, cD, cD);
}

// Round 12
// 256.778 us; speedup vs baseline: 1.0520x; 1.0520x over previous
//
#include <hip/hip_runtime.h>

#define DEV __device__ __forceinline__

typedef unsigned short u16;
typedef float  floatx4 __attribute__((ext_vector_type(4)));
typedef unsigned int uintx2 __attribute__((ext_vector_type(2)));
typedef unsigned int uintx4 __attribute__((ext_vector_type(4)));
typedef __bf16 bf16x8 __attribute__((ext_vector_type(8)));

constexpr int cB = 4, cLQ = 1024, cLKV = 2048, cD = 1024, cH = 16, cHD = 64;

DEV u16 f2bf(float f) {
  unsigned u = __builtin_bit_cast(unsigned, f);
  u += 0x7fffu + ((u >> 16) & 1u);       // round-to-nearest-even
  return (u16)(u >> 16);
}

DEV bf16x8 ld_frag(const u16* p) {
  uintx4 u = *(const uintx4*)p;
  return __builtin_bit_cast(bf16x8, u);
}

DEV floatx4 mfma16(bf16x8 a, bf16x8 b, floatx4 c) {
  return __builtin_amdgcn_mfma_f32_16x16x32_bf16(a, b, c, 0, 0, 0);
}

DEV float ex2(float x) { return __builtin_amdgcn_exp2f(x); }

// pack two f32 -> u32 of 2 bf16 (truncating; P is positive, bias ~0.1%).
DEV unsigned pkbf(float a, float b) {
  return (__builtin_bit_cast(unsigned, b) & 0xffff0000u) |
         (__builtin_bit_cast(unsigned, a) >> 16);
}

// gfx950 dual-register row swaps (VALU, not LDS). HW-validated in v14b.
DEV void pl32(unsigned &a, unsigned &b) {
#if __has_builtin(__builtin_amdgcn_permlane32_swap)
  uintx2 r = __builtin_amdgcn_permlane32_swap(a, b, false, false);
  a = r[0]; b = r[1];
#else
  asm("v_permlane32_swap_b32 %0, %1" : "+v"(a), "+v"(b));
#endif
}
DEV void pl16(unsigned &a, unsigned &b) {
#if __has_builtin(__builtin_amdgcn_permlane16_swap)
  uintx2 r = __builtin_amdgcn_permlane16_swap(a, b, false, false);
  a = r[0]; b = r[1];
#else
  asm("v_permlane16_swap_b32 %0, %1" : "+v"(a), "+v"(b));
#endif
}

// async global->LDS DMA, 16 B/lane; LDS dest = wave-uniform base + lane*16.
// Counts in vmcnt (one unit per call per wave).
DEV void gload16(const u16* g, u16* l) {
  __builtin_amdgcn_global_load_lds(
      (const __attribute__((address_space(1))) void*)g,
      (__attribute__((address_space(3))) void*)l, 16, 0, 0);
}

// Counted-vmcnt barriers (T4): keep newest loads in flight ACROSS the
// barrier; wait only for the tile the next iteration reads.
#define WB4() asm volatile("s_waitcnt vmcnt(4)\n\ts_barrier" ::: "memory")
#define WB0() asm volatile("s_waitcnt vmcnt(0)\n\ts_barrier" ::: "memory")

// ---------------------------------------------------------------------------
// prep v16 (validated r10): LN one wave per row, no barriers, no LDS.
//   [0, 3072):      LN rows (4 per block)
//   [3072, 4096):   W casts fp32->bf16 (4 float4 per thread)
//   4096:           lens from mask + len-descending batch order
// ---------------------------------------------------------------------------
__global__ __launch_bounds__(256) void prep_kernel(
    const float* __restrict__ q, const float* __restrict__ kv,
    const float* __restrict__ nqw, const float* __restrict__ nqb,
    const float* __restrict__ nkw, const float* __restrict__ nkb,
    u16* __restrict__ qn, u16* __restrict__ kvn,
    const float* __restrict__ Wq, const float* __restrict__ Wkv,
    const float* __restrict__ Wo, u16* __restrict__ wqb,
    u16* __restrict__ wkvb, u16* __restrict__ wob,
    const void* __restrict__ mask, int* __restrict__ lens) {
  int bid = blockIdx.x, tid = threadIdx.x;
  if (bid < 3072) {                       // LayerNorm, one WAVE per row
    int row = bid * 4 + (tid >> 6);
    int lane = tid & 63;
    const float* x; const float* w; const float* b; u16* dst;
    if (row < cB * cLQ) {
      x = q + (size_t)row * cD; w = nqw; b = nqb; dst = qn + (size_t)row * cD;
    } else {
      int r2 = row - cB * cLQ;
      x = kv + (size_t)r2 * cD; w = nkw; b = nkb; dst = kvn + (size_t)r2 * cD;
    }
    const float4* xf = (const float4*)x;
    float4 v[4];
    #pragma unroll
    for (int c = 0; c < 4; c++) v[c] = xf[lane + 64 * c];
    float s = 0.f;
    #pragma unroll
    for (int c = 0; c < 4; c++) s += (v[c].x + v[c].y) + (v[c].z + v[c].w);
    #pragma unroll
    for (int m = 1; m < 64; m <<= 1) s += __shfl_xor(s, m, 64);
    float mean = s * (1.f / cD);
    float ss = 0.f;
    #pragma unroll
    for (int c = 0; c < 4; c++) {
      v[c].x -= mean; v[c].y -= mean; v[c].z -= mean; v[c].w -= mean;
      ss += (v[c].x * v[c].x + v[c].y * v[c].y) +
            (v[c].z * v[c].z + v[c].w * v[c].w);
    }
    #pragma unroll
    for (int m = 1; m < 64; m <<= 1) ss += __shfl_xor(ss, m, 64);
    float rs = rsqrtf(ss * (1.f / cD) + 1e-5f);
    const float4* wf = (const float4*)w;
    const float4* bf = (const float4*)b;
    #pragma unroll
    for (int c = 0; c < 4; c++) {
      float4 wv = wf[lane + 64 * c];
      float4 bv = bf[lane + 64 * c];
      ushort4 o;
      o.x = f2bf(v[c].x * rs * wv.x + bv.x);
      o.y = f2bf(v[c].y * rs * wv.y + bv.y);
      o.z = f2bf(v[c].z * rs * wv.z + bv.z);
      o.w = f2bf(v[c].w * rs * wv.w + bv.w);
      ((ushort4*)dst)[lane + 64 * c] = o;
    }
  } else if (bid < 4096) {                // weight casts, 4 float4/thread
    int base = (bid - 3072) * 1024;
    #pragma unroll
    for (int c = 0; c < 4; c++) {
      int gi = base + c * 256 + tid;      // quad idx 0..1M
      const float* src; u16* dst; int off;
      if (gi < 262144)      { src = Wq;  dst = wqb;  off = gi; }
      else if (gi < 786432) { src = Wkv; dst = wkvb; off = gi - 262144; }
      else                  { src = Wo;  dst = wob;  off = gi - 786432; }
      float4 v = ((const float4*)src)[off];
      ushort4 o;
      o.x = f2bf(v.x); o.y = f2bf(v.y); o.z = f2bf(v.z); o.w = f2bf(v.w);
      ((ushort4*)dst)[off] = o;
    }
  } else {                                // lens (monotone suffix mask)
    __shared__ int smode;
    __shared__ int cnt[cB];
    if (tid == 0) smode = 0;
    if (tid < cB) cnt[tid] = 0;
    __syncthreads();
    const unsigned* mi = (const unsigned*)mask;
    int bad = 0;
    for (int i = tid; i < cB * cLKV / 4; i += 256)
      if (mi[i] > 1u) bad = 1;
    if (bad) smode = 1;
    __syncthreads();
    if (smode == 0) {                     // int32 mask
      for (int b = 0; b < cB; b++) {
        int c = 0;
        for (int i = tid; i < cLKV; i += 256) c += (mi[(size_t)b * cLKV + i] == 0u);
        atomicAdd(&cnt[b], c);
      }
    } else {                              // uint8 mask
      const unsigned char* m8 = (const unsigned char*)mask;
      for (int b = 0; b < cB; b++) {
        int c = 0;
        for (int i = tid; i < cLKV; i += 256) c += (m8[(size_t)b * cLKV + i] == 0);
        atomicAdd(&cnt[b], c);
      }
    }
    __syncthreads();
    if (tid < cB) lens[tid] = cnt[tid];
    if (tid == 0) {                       // order[4] = batches, len-descending
      int ord[4] = {0, 1, 2, 3};
      #pragma unroll
      for (int a = 0; a < 3; a++)
        #pragma unroll
        for (int d = 0; d < 3; d++)
          if (cnt[ord[d]] < cnt[ord[d + 1]]) {
            int tswap = ord[d]; ord[d] = ord[d + 1]; ord[d + 1] = tswap;
          }
      #pragma unroll
      for (int a = 0; a < 4; a++) lens[4 + a] = ord[a];
    }
  }
}

// ---------------------------------------------------------------------------
// proj v18: 128² tile + global_load_lds DMA staging + 3-slot LDS ring with
// COUNTED vmcnt (T4). Why v10's gload_lds failed and this shouldn't: v10's
// single-barrier loop drained vmcnt(0) one compute phase after issue (zero
// slack). Here the ring gives each tile's DMA TWO compute phases (~500cy) of
// flight, and the barrier waits only vmcnt(4) — tile i+2's loads cross it.
// Per-iter wave ops: 12 ds_read + 16 MFMA, NO ds_writes (-25% DS issue), no
// staging VGPRs (v11's regalloc trap has nothing to pin), no staging VALU.
// LDS 3*(8K+8K) = 48KB -> 3 blocks/CU (12 waves). Hazards:
//  - iter i reads slot i%3: landed by end-of-iter-(i-1) vmcnt(4) (only tile
//    i+1 outstanding then). Prologue: issue t0,t1 -> vmcnt(4) = t0 landed.
//  - DMA writes slot (i+2)%3; waves read slot i%3; slot (i+1)%3 idle. No
//    collision; barriers keep waves in the same iter.
//  - tail: iter T-2 issues nothing -> vmcnt(0); iter T-1 no barrier needed.
// Grid 1280 as v15: [0,256) Q-proj, [256,1280) KV-proj; mask-skip validated.
// ---------------------------------------------------------------------------
__global__ __launch_bounds__(256) void proj_fused(
    const u16* __restrict__ qn, const u16* __restrict__ wqb,
    const float* __restrict__ bq, u16* __restrict__ qhb,
    const u16* __restrict__ kvn, const u16* __restrict__ wkvb,
    const float* __restrict__ bkv, u16* __restrict__ khb,
    u16* __restrict__ vthb, const int* __restrict__ lens) {
  __shared__ __align__(16) u16 As[3 * 128 * 32];   // 24 KB
  __shared__ __align__(16) u16 Bs[3 * 128 * 32];   // 24 KB
  int bid = blockIdx.x;
  int tid = threadIdx.x;
  int lane = tid & 63;
  int m16 = lane & 15, quad = lane >> 4;
  int wave = tid >> 6;
  int wr = wave >> 1, wc = wave & 1;

  bool isQ = bid < 256;
  int row0, col0;
  const u16* A; const u16* Bm; const float* bias;
  if (isQ) {
    row0 = (bid >> 3) * 128; col0 = (bid & 7) * 128;
    A = qn; Bm = wqb; bias = bq;
  } else {
    int b2 = bid - 256;
    row0 = (b2 >> 4) * 128; col0 = (b2 & 15) * 128;
    A = kvn; Bm = wkvb; bias = bkv;
    if ((row0 & (cLKV - 1)) >= lens[row0 >> 11]) return;  // masked tile skip
  }
  const int K = cD;
  constexpr int T = cD / 32;              // 32 K-tiles

  // DMA staging map (derivation in header): call j of wave w fills LDS rows
  // [(w+4j)*16, +16) of the slot; lane l's 16B -> row +l/4, col (l&3)*8; the
  // matching per-lane GLOBAL address makes layout linear [row][32 u16].
  int l4 = lane >> 2;                     // 0..15
  int l2 = (lane & 3) * 8;                // u16 col
  const u16* ga0 = A + (size_t)(row0 + wave * 16 + l4) * K + l2;
  const u16* ga1 = ga0 + (size_t)64 * K;
  const u16* gb0 = Bm + (size_t)(col0 + wave * 16 + l4) * K + l2;
  const u16* gb1 = gb0 + (size_t)64 * K;
  u16* dAw = As + wave * 512;             // + slot*4096; +2048 for j=1
  u16* dBw = Bs + wave * 512;

#define ISSUE(kk, slot) do { \
    u16* dA_ = dAw + (slot) * 4096; \
    u16* dB_ = dBw + (slot) * 4096; \
    gload16(ga0 + (kk), dA_); \
    gload16(ga1 + (kk), dA_ + 2048); \
    gload16(gb0 + (kk), dB_); \
    gload16(gb1 + (kk), dB_ + 2048); \
  } while (0)

  // prologue: tiles 0,1 in flight; wait tile 0 only
  ISSUE(0, 0);
  ISSUE(32, 1);
  WB4();

  floatx4 z = {0.f, 0.f, 0.f, 0.f};
  floatx4 acc[4][4];
  #pragma unroll
  for (int i = 0; i < 4; i++)
    #pragma unroll
    for (int j = 0; j < 4; j++) acc[i][j] = z;

  #pragma unroll 3
  for (int i = 0; i < T; i++) {
    int slot = i % 3;
    if (i + 2 < T) ISSUE((i + 2) * 32, (i + 2) % 3);
    const u16* rA = As + slot * 4096;
    const u16* rB = Bs + slot * 4096;
    bf16x8 af[4], bfr[4];
    #pragma unroll
    for (int ii = 0; ii < 4; ii++)
      af[ii] = ld_frag(&rA[(wr * 64 + ii * 16 + m16) * 32 + quad * 8]);
    #pragma unroll
    for (int j = 0; j < 4; j++)
      bfr[j] = ld_frag(&rB[(wc * 64 + j * 16 + m16) * 32 + quad * 8]);
    #pragma unroll
    for (int ii = 0; ii < 4; ii++)
      #pragma unroll
      for (int j = 0; j < 4; j++)
        acc[ii][j] = mfma16(af[ii], bfr[j], acc[ii][j]);
    if (i + 2 < T) WB4();                 // tile i+1 landed; i+2 in flight
    else if (i + 1 < T) WB0();            // last tile must land
  }
#undef ISSUE

  // epilogue: C/D layout col=lane&15, row=quad*4+reg
  #pragma unroll
  for (int j = 0; j < 4; j++) {
    int col = col0 + wc * 64 + j * 16 + m16;
    float bs = bias[col];
    if (isQ) {
      #pragma unroll
      for (int i = 0; i < 4; i++) {
        int crow = row0 + wr * 64 + i * 16 + quad * 4;
        #pragma unroll
        for (int r = 0; r < 4; r++)
          qhb[(size_t)(crow + r) * cD + col] =
              f2bf((acc[i][j][r] + bs) * 0.18033688f);   // 0.125 * log2(e)
      }
    } else {
      bool isK = col < cD;
      int c2 = isK ? col : col - cD;
      int hh = c2 >> 6, dd = c2 & 63;
      #pragma unroll
      for (int i = 0; i < 4; i++) {
        int crow = row0 + wr * 64 + i * 16 + quad * 4;
        int bb = crow >> 11, kvp = crow & (cLKV - 1);
        if (isK) {
          u16* dst = khb + ((size_t)(bb * cH + hh) * cLKV + kvp) * 64 + dd;
          #pragma unroll
          for (int r = 0; r < 4; r++) dst[(size_t)r * 64] = f2bf(acc[i][j][r] + bs);
        } else {
          u16* dst = vthb + ((size_t)(bb * cH + hh) * 64 + dd) * cLKV + kvp;
          ushort4 o;
          o.x = f2bf(acc[i][j][0] + bs);
          o.y = f2bf(acc[i][j][1] + bs);
          o.z = f2bf(acc[i][j][2] + bs);
          o.w = f2bf(acc[i][j][3] + bs);
          *(ushort4*)dst = o;
        }
      }
    }
  }
}

// ---------------------------------------------------------------------------
// O-proj v16 (validated r10): 64x128 tiles -> 512 blocks @ 24KB LDS, all
// co-resident (2 blocks/CU). Per-wave 32x64 output (acc[2][4]).
// ---------------------------------------------------------------------------
__global__ __launch_bounds__(256) void gemm_o(
    const u16* __restrict__ A, const u16* __restrict__ Bm,
    const float* __restrict__ bias, const float* __restrict__ res,
    float* __restrict__ Cout, int N, int K) {
  __shared__ __align__(16) u16 As[2 * 64 * 32];    //  8 KB
  __shared__ __align__(16) u16 Bs[2 * 128 * 32];   // 16 KB
  int lane = threadIdx.x & 63;
  int m16 = lane & 15, quad = lane >> 4;
  int wave = threadIdx.x >> 6;
  int wr = wave >> 1, wc = wave & 1;
  int row0 = blockIdx.y * 64, col0 = blockIdx.x * 128;

  int tid = threadIdx.x;
  int srow = tid >> 2;                    // 0..63
  int sseg = (tid & 3) * 8;
  const u16* ga = A + (size_t)(row0 + srow) * K + sseg;
  const u16* gb = Bm + (size_t)(col0 + srow) * K + sseg;
  const size_t rstep = (size_t)64 * K;
  int woff = srow * 32 + sseg;

  // tile 0 -> buf0
  uintx4 a0 = *(const uintx4*)ga;
  uintx4 b0 = *(const uintx4*)gb;
  uintx4 b1 = *(const uintx4*)(gb + rstep);
  *(uintx4*)(As + woff) = a0;
  *(uintx4*)(Bs + woff) = b0;
  *(uintx4*)(Bs + woff + 2048) = b1;
  // prefetch tile 1
  a0 = *(const uintx4*)(ga + 32);
  b0 = *(const uintx4*)(gb + 32);
  b1 = *(const uintx4*)(gb + rstep + 32);
  __syncthreads();

  floatx4 z = {0.f, 0.f, 0.f, 0.f};
  floatx4 acc[2][4];
  #pragma unroll
  for (int i = 0; i < 2; i++)
    #pragma unroll
    for (int j = 0; j < 4; j++) acc[i][j] = z;

  for (int k0 = 0; k0 < K; k0 += 32) {
    int cur = (k0 >> 5) & 1;
    const u16* rA = As + cur * 2048;
    const u16* rB = Bs + cur * 4096;
    bf16x8 af[2], bfr[4];
    #pragma unroll
    for (int i = 0; i < 2; i++)
      af[i] = ld_frag(&rA[(wr * 32 + i * 16 + m16) * 32 + quad * 8]);
    #pragma unroll
    for (int j = 0; j < 4; j++)
      bfr[j] = ld_frag(&rB[(wc * 64 + j * 16 + m16) * 32 + quad * 8]);
    if (k0 + 32 < K) {                    // stage next tile into other buffer
      u16* nA = As + (cur ^ 1) * 2048 + woff;
      u16* nB = Bs + (cur ^ 1) * 4096 + woff;
      *(uintx4*)nA = a0;
      *(uintx4*)nB = b0;
      *(uintx4*)(nB + 2048) = b1;
      if (k0 + 64 < K) {                  // prefetch tile k0+64
        a0 = *(const uintx4*)(ga + k0 + 64);
        b0 = *(const uintx4*)(gb + k0 + 64);
        b1 = *(const uintx4*)(gb + rstep + k0 + 64);
      }
    }
    #pragma unroll
    for (int i = 0; i < 2; i++)
      #pragma unroll
      for (int j = 0; j < 4; j++)
        acc[i][j] = mfma16(af[i], bfr[j], acc[i][j]);
    __syncthreads();
  }

  #pragma unroll
  for (int j = 0; j < 4; j++) {
    int col = col0 + wc * 64 + j * 16 + m16;
    float bs = bias[col];
    #pragma unroll
    for (int i = 0; i < 2; i++) {
      int crow = row0 + wr * 32 + i * 16 + quad * 4;
      #pragma unroll
      for (int r = 0; r < 4; r++) {
        size_t idx = (size_t)(crow + r) * N + col;
        Cout[idx] = acc[i][j][r] + bs + res[idx];
      }
    }
  }
}

// ---------------------------------------------------------------------------
// Flash cross-attention v14 (HW-validated round 8): q32 structure + P path
// fully in registers via dual-register permlane swaps (8 swaps + 8 packs per
// group replace 12 DS ops/chunk). LDS 18.4 KB.
// ---------------------------------------------------------------------------
constexpr int KS = 72;   // K/V LDS row stride (u16): 144 B, 16B-aligned

template<bool MASK>
DEV void attn_compute(int k0, int len, const u16* __restrict__ Kt,
                      const u16* __restrict__ Vt,
                      const bf16x8 (&qf)[2][2], int m16, int quad,
                      float (&lsum)[2], floatx4 (&accO)[2][4]) {
  floatx4 z = {0.f, 0.f, 0.f, 0.f};
  // K fragments loaded ONCE, used by both q-groups.
  // QK^T swapped: A = K (row = kv = t*16+m16, k = d), B = Q (col = q)
  bf16x8 kf[4][2];
  #pragma unroll
  for (int t = 0; t < 4; t++) {
    kf[t][0] = ld_frag(&Kt[(t * 16 + m16) * KS + quad * 8]);
    kf[t][1] = ld_frag(&Kt[(t * 16 + m16) * KS + 32 + quad * 8]);
  }
  floatx4 s[2][4];
  #pragma unroll
  for (int g = 0; g < 2; g++)
    #pragma unroll
    for (int t = 0; t < 4; t++) {
      floatx4 tt = z;
      tt = mfma16(kf[t][0], qf[g][0], tt);
      tt = mfma16(kf[t][1], qf[g][1], tt);
      s[g][t] = tt;
    }
  // exp2 -> packed bf16 pairs in regs; p[t][j]: j-th bf16x2 of tile t
  bf16x8 ap0[2], ap1[2];
  #pragma unroll
  for (int g = 0; g < 2; g++) {
    unsigned p[4][2];
    #pragma unroll
    for (int t = 0; t < 4; t++) {
      float e0, e1, e2, e3;
      if (MASK) {
        int key = k0 + t * 16 + quad * 4;
        e0 = (key     < len) ? ex2(s[g][t][0]) : 0.f;
        e1 = (key + 1 < len) ? ex2(s[g][t][1]) : 0.f;
        e2 = (key + 2 < len) ? ex2(s[g][t][2]) : 0.f;
        e3 = (key + 3 < len) ? ex2(s[g][t][3]) : 0.f;
      } else {
        e0 = ex2(s[g][t][0]);
        e1 = ex2(s[g][t][1]);
        e2 = ex2(s[g][t][2]);
        e3 = ex2(s[g][t][3]);
      }
      lsum[g] += (e0 + e1) + (e2 + e3);
      p[t][0] = pkbf(e0, e1);
      p[t][1] = pkbf(e2, e3);
    }
    // redistribute: 2 swaps per register pair, no selects
    unsigned a0 = p[0][0], b0 = p[1][0]; pl32(a0, b0); pl16(a0, b0);
    unsigned a1 = p[0][1], b1 = p[1][1]; pl32(a1, b1); pl16(a1, b1);
    uintx4 lo = {a0, a1, b0, b1};
    unsigned c0 = p[2][0], d0 = p[3][0]; pl32(c0, d0); pl16(c0, d0);
    unsigned c1 = p[2][1], d1 = p[3][1]; pl32(c1, d1); pl16(c1, d1);
    uintx4 hi = {c0, c1, d0, d1};
    ap0[g] = __builtin_bit_cast(bf16x8, lo);   // kv 0..31 (k = quad*8+0..7)
    ap1[g] = __builtin_bit_cast(bf16x8, hi);   // kv 32..63
  }
  // PV: A = P in regs (row = q, k = kv), B = V (col = d); bv loaded once
  // for both groups.
  #pragma unroll
  for (int db = 0; db < 4; db++) {
    bf16x8 bv0 = ld_frag(&Vt[(db * 16 + m16) * KS + quad * 8]);
    bf16x8 bv1 = ld_frag(&Vt[(db * 16 + m16) * KS + 32 + quad * 8]);
    #pragma unroll
    for (int g = 0; g < 2; g++) {
      accO[g][db] = mfma16(ap0[g], bv0, accO[g][db]);
      accO[g][db] = mfma16(ap1[g], bv1, accO[g][db]);
    }
  }
}

__global__ __launch_bounds__(256) void attn_kernel(
    const u16* __restrict__ qh, const u16* __restrict__ kh,
    const u16* __restrict__ vth, const int* __restrict__ lens,
    u16* __restrict__ out) {
  int bid = blockIdx.x;                   // 0..511
  int r = bid >> 7;                       // 0..3
  int rank = r ^ (r >> 1);                // {0,1,3,2}: pair long+short per CU
  int b = lens[4 + rank];
  int combo = bid & 127;
  int h = combo >> 3;                     // 0..15
  int qt = combo & 7;                     // 0..7 (128 q-rows per block)
  int len = lens[b];
  int wave = threadIdx.x >> 6, lane = threadIdx.x & 63;
  int m16 = lane & 15, quad = lane >> 4;

  __shared__ __align__(16) u16 Kt[64 * KS];
  __shared__ __align__(16) u16 Vt[64 * KS];

  // Q as B-operand: two 16-q groups per wave; col = q, k = d
  int q0 = qt * 128 + wave * 32;
  const u16* qp = qh + ((size_t)(b * cLQ + q0 + m16) * cH + h) * cHD;
  bf16x8 qf[2][2];
  qf[0][0] = ld_frag(qp + quad * 8);
  qf[0][1] = ld_frag(qp + 32 + quad * 8);
  qf[1][0] = ld_frag(qp + (size_t)16 * cD + quad * 8);
  qf[1][1] = ld_frag(qp + (size_t)16 * cD + 32 + quad * 8);

  const u16* kbase = kh + (size_t)(b * cH + h) * cLKV * cHD;
  const u16* vbase = vth + (size_t)(b * cH + h) * cHD * cLKV;

  int srow = threadIdx.x >> 3;   // 0..31
  int sseg = threadIdx.x & 7;    // 0..7 (16B segment)
  const u16* kg = kbase + (size_t)srow * cHD + sseg * 8;
  const u16* vg = vbase + (size_t)srow * cLKV + sseg * 8;

  float lsum[2] = {0.f, 0.f};
  floatx4 z = {0.f, 0.f, 0.f, 0.f};
  floatx4 accO[2][4] = {{z, z, z, z}, {z, z, z, z}};

  int nch = (len + 63) >> 6;
  // prefetch chunk 0
  uintx4 ka  = *(const uintx4*)kg;
  uintx4 kb2 = *(const uintx4*)(kg + (size_t)32 * cHD);
  uintx4 va  = *(const uintx4*)vg;
  uintx4 vb  = *(const uintx4*)(vg + (size_t)32 * cLKV);

  for (int c = 0; c < nch; c++) {
    int k0 = c * 64;
    __syncthreads();
    *(uintx4*)&Kt[srow * KS + sseg * 8] = ka;
    *(uintx4*)&Kt[(srow + 32) * KS + sseg * 8] = kb2;
    *(uintx4*)&Vt[srow * KS + sseg * 8] = va;
    *(uintx4*)&Vt[(srow + 32) * KS + sseg * 8] = vb;
    if (c + 1 < nch) {
      int kn = k0 + 64;
      ka  = *(const uintx4*)(kg + (size_t)kn * cHD);
      kb2 = *(const uintx4*)(kg + (size_t)(kn + 32) * cHD);
      va  = *(const uintx4*)(vg + kn);
      vb  = *(const uintx4*)(vg + (size_t)32 * cLKV + kn);
    }
    __syncthreads();
    if (k0 + 64 <= len)
      attn_compute<false>(k0, len, Kt, Vt, qf, m16, quad, lsum, accO);
    else
      attn_compute<true>(k0, len, Kt, Vt, qf, m16, quad, lsum, accO);
  }

  // softmax denominators per group: lane owns q = g*16+m16; reduce quads
  #pragma unroll
  for (int g = 0; g < 2; g++) {
    float tsum = lsum[g];
    tsum += __shfl_xor(tsum, 16, 64);
    tsum += __shfl_xor(tsum, 32, 64);
    #pragma unroll
    for (int rr = 0; rr < 4; rr++) {
      float inv = 1.0f / __shfl(tsum, quad * 4 + rr, 16);
      int qg = q0 + g * 16 + quad * 4 + rr;
      size_t base = ((size_t)(b * cLQ + qg) * cH + h) * cHD;
      #pragma unroll
      for (int db = 0; db < 4; db++)
        out[base + db * 16 + m16] = f2bf(accO[g][db][rr] * inv);
    }
  }
}

// ---------------------------------------------------------------------------
extern "C" void kernel_launch(void* const* d_in, const int* in_sizes, int n_in,
                              void* d_out, int out_size, void* d_ws, size_t ws_size,
                              hipStream_t stream) {
  const float* q    = (const float*)d_in[0];
  const float* kv   = (const float*)d_in[1];
  const void*  mask = d_in[2];
  const float* nqw  = (const float*)d_in[3];
  const float* nqb  = (const float*)d_in[4];
  const float* nkw  = (const float*)d_in[5];
  const float* nkb  = (const float*)d_in[6];
  const float* Wq   = (const float*)d_in[7];
  const float* bq   = (const float*)d_in[8];
  const float* Wkv  = (const float*)d_in[9];
  const float* bkv  = (const float*)d_in[10];
  const float* Wo   = (const float*)d_in[11];
  const float* bo   = (const float*)d_in[12];
  float* out = (float*)d_out;

  char* w = (char*)d_ws;
  int* lens = (int*)w;       w += 256;
  u16* qn   = (u16*)w;       w += (size_t)cB * cLQ * cD * 2;        // 8 MB
  u16* kvn  = (u16*)w;       w += (size_t)cB * cLKV * cD * 2;       // 16 MB
  u16* wqb  = (u16*)w;       w += (size_t)cD * cD * 2;              // 2 MB
  u16* wkvb = (u16*)w;       w += (size_t)2 * cD * cD * 2;          // 4 MB
  u16* wob  = (u16*)w;       w += (size_t)cD * cD * 2;              // 2 MB
  u16* qhb  = (u16*)w;       w += (size_t)cB * cLQ * cD * 2;        // 8 MB
  u16* khb  = (u16*)w;       w += (size_t)cB * cH * cLKV * cHD * 2; // 16 MB
  u16* vthb = (u16*)w;       w += (size_t)cB * cH * cHD * cLKV * 2; // 16 MB
  u16* aob  = (u16*)w;                                              // 8 MB

  prep_kernel<<<4097, 256, 0, stream>>>(
      q, kv, nqw, nqb, nkw, nkb, qn, kvn,
      Wq, Wkv, Wo, wqb, wkvb, wob, mask, lens);
  proj_fused<<<1280, 256, 0, stream>>>(
      qn, wqb, bq, qhb, kvn, wkvb, bkv, khb, vthb, lens);
  attn_kernel<<<512, 256, 0, stream>>>(
      qhb, khb, vthb, lens, aob);
  gemm_o<<<dim3(cD / 128, cB * cLQ / 64), 256, 0, stream>>>(
      aob, wob, bo, q, out, cD, cD);
}